// Round 1
// baseline (250.517 us; speedup 1.0000x reference)
//
#include <hip/hip_runtime.h>
#include <float.h>

#define NB 64  // n_bins (bins array has NB+1 edges)

typedef float vfloat4 __attribute__((ext_vector_type(4)));

// Persistent grid-stride version. 2048 blocks (8 wg/CU x 256 CU), each block
// loops over ~7.6 chunks of 1024 float4-slots (16 KB contiguous per chunk).
// Rationale: the previous 15625-short-block version paid a serial setup
// prologue (bins loads + fdiv + __syncthreads + LDS reads) per block, ~61
// times per CU, leaving the store queue empty between blocks. Grid-stride
// amortizes setup 7.6x and keeps a continuous store stream per wave.
// Next chunk's x-loads are issued BEFORE the current chunk's stores so the
// compiler's vmcnt wait on the loads does not require draining the in-order
// store queue (vmem ops retire in issue order).
// Stores remain PLAIN (write-back L2): nt-flagged stores measured ~3.1 TB/s
// in a prior session vs 6.3 TB/s for plain.
__global__ __launch_bounds__(256) void ple_kernel(const float* __restrict__ x,
                                                  const float* __restrict__ bins,
                                                  float* __restrict__ out,
                                                  unsigned total4) {
    __shared__ __align__(16) float s_rinv[NB];
    __shared__ __align__(16) float s_nlor[NB];
    __shared__ __align__(16) float s_cl[NB];
    __shared__ __align__(16) float s_ch[NB];

    const int tid = threadIdx.x;
    if (tid < NB) {
        const float lo   = bins[tid];
        const float hi   = bins[tid + 1];
        const float rinv = 1.0f / (hi - lo);   // once per block (2048 blocks now)
        s_rinv[tid] = rinv;
        s_nlor[tid] = -lo * rinv;
        s_cl[tid] = (tid == 0)      ? -FLT_MAX : 0.0f;   // bin 0: no left clamp
        s_ch[tid] = (tid == NB - 1) ?  FLT_MAX : 1.0f;   // bin 63: no right clamp
    }
    __syncthreads();

    const int j4 = (tid & 15) << 2;            // this thread's 4 bins (loop-invariant)
    const vfloat4 rinv4 = *(const vfloat4*)&s_rinv[j4];
    const vfloat4 nlor4 = *(const vfloat4*)&s_nlor[j4];
    const vfloat4 cl4   = *(const vfloat4*)&s_cl[j4];
    const vfloat4 ch4   = *(const vfloat4*)&s_ch[j4];

    // 32-bit indexing: total4 <= 1.6e7 for BATCH=1e6; byte offsets < 2^32.
    const unsigned step = (unsigned)gridDim.x << 10;       // slots per grid pass
    unsigned base = ((unsigned)blockIdx.x << 10) + (unsigned)tid;

    // prologue: loads for the first chunk
    float xv[4];
#pragma unroll
    for (int k = 0; k < 4; ++k) {
        const unsigned t = base + (unsigned)(k << 8);
        xv[k] = (t < total4) ? x[t >> 4] : 0.0f;
    }

    while (base < total4) {
        const unsigned nbase = base + step;

        // issue next chunk's loads first (predicated off past the end)
        float xn[4];
#pragma unroll
        for (int k = 0; k < 4; ++k) {
            const unsigned t = nbase + (unsigned)(k << 8);
            xn[k] = (t < total4) ? x[t >> 4] : 0.0f;
        }

        // compute + store current chunk (4 x 1KB contiguous per wave-store)
#pragma unroll
        for (int k = 0; k < 4; ++k) {
            const unsigned t = base + (unsigned)(k << 8);
            vfloat4 r;
#pragma unroll
            for (int c = 0; c < 4; ++c) {
                const float v = fmaf(xv[k], rinv4[c], nlor4[c]);
                r[c] = fminf(fmaxf(v, cl4[c]), ch4[c]);
            }
            if (t < total4)
                *((vfloat4*)out + t) = r;      // plain store (write-back L2 path)
        }

#pragma unroll
        for (int k = 0; k < 4; ++k) xv[k] = xn[k];
        base = nbase;
    }
}

extern "C" void kernel_launch(void* const* d_in, const int* in_sizes, int n_in,
                              void* d_out, int out_size, void* d_ws, size_t ws_size,
                              hipStream_t stream) {
    const float* x    = (const float*)d_in[0];
    const float* bins = (const float*)d_in[1];
    float* out        = (float*)d_out;

    const int batch = in_sizes[0];                        // x is (BATCH, 1)
    const unsigned total4 = (unsigned)batch * (NB / 4);   // float4 slots
    const unsigned chunks = (total4 + 1023) / 1024;       // 15625 for BATCH=1e6
    const unsigned grid = chunks < 2048u ? chunks : 2048u; // 8 wg/CU persistent

    ple_kernel<<<(dim3)grid, 256, 0, stream>>>(x, bins, out, total4);
}